// Round 10
// baseline (360.911 us; speedup 1.0000x reference)
//
#include <hip/hip_runtime.h>
#include <hip/hip_fp16.h>

#define N_NODES 200000
#define N_EDGES 6400000
#define F_IN 34
#define F_HID 10
#define F_OUT 4
#define HPAD 12              // fb path only: 48B fp32 rows
#define BINS 782             // dst buckets
#define NPB 256              // nodes per bucket: 782*256 = 200192 >= N
#define CHUNK 12288
#define BLK1 ((N_EDGES + CHUNK - 1) / CHUNK)    // 521
#define SCAN_L (BINS * BLK1)                    // 407422
#define NA ((SCAN_L + 511) / 512)               // 796 (<= 1024 for scanB)
#define ACCP 11              // fallback-arm LDS acc padding
#define SORT_CAP 12288       // 48KB LDS; bucket avg 8184, sigma~90

typedef float floatx4 __attribute__((ext_vector_type(4)));   // nontemporal-store-compatible

// ---------------------------------------------------------------- helpers
__device__ __forceinline__ float2 up2(unsigned u) {
    __half2 h = *reinterpret_cast<const __half2*>(&u);
    return __half22float2(h);
}

// ---------------------------------------------------------------- mode detect
// int64 edge_index => every odd 32-bit word is zero (values < 2^31).
__global__ void detect_mode_kernel(const int* __restrict__ ei, int* __restrict__ mode) {
    int t = threadIdx.x;                 // 64 threads
    int v = ei[2 * t + 1];
    unsigned long long b = __ballot(v != 0);
    if (t == 0) *mode = (b == 0ull) ? 1 : 0;
}

__device__ __forceinline__ int nt_idx(const int* ei, long long elem, int mode) {
    return mode ? __builtin_nontemporal_load(ei + 2 * elem)
                : __builtin_nontemporal_load(ei + elem);
}
__device__ __forceinline__ int load_idx(const int* ei, long long elem, int mode) {
    return mode ? ei[2 * elem] : ei[elem];
}

// ---------------------------------------------------------------- pass 1: bucket counts (LDS hist)
__global__ void p1_count_kernel(const int* __restrict__ ei,
                                const int* __restrict__ mode_p,
                                int* __restrict__ bcnt) {
    __shared__ int hist[BINS];
    const int mode = *mode_p;
    int t = threadIdx.x;
    for (int j = t; j < BINS; j += blockDim.x) hist[j] = 0;
    __syncthreads();

    long long base = (long long)blockIdx.x * CHUNK;
    for (int k = t; k < CHUNK; k += blockDim.x) {
        long long e = base + k;
        if (e >= N_EDGES) break;
        int d = nt_idx(ei, (long long)N_EDGES + e, mode);
        if ((unsigned)d < (unsigned)N_NODES) atomicAdd(&hist[d >> 8], 1);
    }
    __syncthreads();
    for (int j = t; j < BINS; j += blockDim.x)
        bcnt[j * BLK1 + blockIdx.x] = hist[j];   // bin-major
}

// ---------------------------------------------------------------- scan A: per-512-block sums
__global__ void scanA_kernel(const int* __restrict__ src, int* __restrict__ bsum) {
    __shared__ int s[512];
    int t = threadIdx.x;
    int i = blockIdx.x * 512 + t;
    s[t] = (i < SCAN_L) ? src[i] : 0;
    __syncthreads();
    for (int o = 256; o > 0; o >>= 1) {
        if (t < o) s[t] += s[t + o];
        __syncthreads();
    }
    if (t == 0) bsum[blockIdx.x] = s[0];
}

// ---------------------------------------------------------------- scan B: exclusive scan of NA block sums
__global__ void scanB_kernel(int* __restrict__ bsum, int* __restrict__ total) {
    __shared__ int s[1024];
    int t = threadIdx.x;
    int v = (t < NA) ? bsum[t] : 0;
    s[t] = v;
    __syncthreads();
    for (int o = 1; o < 1024; o <<= 1) {
        int u = (t >= o) ? s[t - o] : 0;
        __syncthreads();
        s[t] += u;
        __syncthreads();
    }
    if (t < NA) bsum[t] = s[t] - v;             // exclusive block offset
    if (t == 1023) *total = s[t];
}

// ---------------------------------------------------------------- scan C: produce boff (512-granule)
__global__ void scanC_kernel(const int* __restrict__ src,
                             const int* __restrict__ bsum,
                             int* __restrict__ dst) {
    __shared__ int s[512];
    int t = threadIdx.x;
    int i = blockIdx.x * 512 + t;
    int v = (i < SCAN_L) ? src[i] : 0;
    s[t] = v;
    __syncthreads();
    for (int o = 1; o < 512; o <<= 1) {
        int u = (t >= o) ? s[t - o] : 0;
        __syncthreads();
        s[t] += u;
        __syncthreads();
    }
    if (i < SCAN_L) dst[i] = bsum[blockIdx.x] + s[t] - v;  // exclusive prefix
}

// ---------------------------------------------------------------- pass 3: bucket fill (LDS cursors)
__global__ void p3_fill_kernel(const int* __restrict__ ei,
                               const int* __restrict__ mode_p,
                               const int* __restrict__ boff,
                               int* __restrict__ ebuf) {
    __shared__ int cur[BINS];
    const int mode = *mode_p;
    int t = threadIdx.x;
    for (int j = t; j < BINS; j += blockDim.x) cur[j] = boff[j * BLK1 + blockIdx.x];
    __syncthreads();

    long long base = (long long)blockIdx.x * CHUNK;
    for (int k = t; k < CHUNK; k += blockDim.x) {
        long long e = base + k;
        if (e >= N_EDGES) break;
        int d = nt_idx(ei, (long long)N_EDGES + e, mode);
        if ((unsigned)d >= (unsigned)N_NODES) continue;
        int s = nt_idx(ei, e, mode);
        s = min(max(s, 0), N_NODES - 1);         // memory-safety clamp (input always valid)
        int bin = d >> 8;
        int ld = d & 255;
        int pos = atomicAdd(&cur[bin], 1);
        ebuf[pos] = s | (ld << 18);              // src:18 bits | local_dst:8 bits
    }
}

// ---------------------------------------------------------------- pass 5: per-bucket counting
// sort by LOCAL DST (LDS, in-place in ebuf) -> dst-sorted edges + nodeoff + per-node dis
// written into the 32B hpk row (byte 20). flag[b] records sortedness for p4b's fast arm.
__global__ void p5_sort_kernel(int* __restrict__ ebuf,
                               const int* __restrict__ boff,
                               const int* __restrict__ total,
                               uint4* __restrict__ hpk,
                               int* __restrict__ nodeoff,
                               int* __restrict__ flag) {
    __shared__ int buf[SORT_CAP];
    __shared__ int cnt[NPB];
    __shared__ int sc[NPB];
    __shared__ int cur[NPB];

    int b = blockIdx.x;
    int t = threadIdx.x;
    if (t < NPB) cnt[t] = 0;
    __syncthreads();

    int start = boff[b * BLK1];
    int end = (b < BINS - 1) ? boff[(b + 1) * BLK1] : *total;
    int n = end - start;
    bool fit = (n <= SORT_CAP);

    for (int k = t; k < n; k += blockDim.x) {
        int v = __builtin_nontemporal_load(ebuf + start + k);
        atomicAdd(&cnt[((unsigned)v) >> 18], 1);
        if (fit) buf[k] = v;
    }
    __syncthreads();

    // exclusive scan of cnt (256 entries, threads t<256)
    if (t < NPB) sc[t] = cnt[t];
    __syncthreads();
    for (int o = 1; o < NPB; o <<= 1) {
        int u = (t < NPB && t >= o) ? sc[t - o] : 0;
        __syncthreads();
        if (t < NPB) sc[t] += u;
        __syncthreads();
    }
    if (t < NPB) {
        int excl = sc[t] - cnt[t];
        nodeoff[b * NPB + t] = start + excl;
        cur[t] = start + excl;               // ABSOLUTE cursor
        int i = b * NPB + t;
        if (i < N_NODES) {
            float dis = rsqrtf((float)(cnt[t] + 1));   // +1 self-loop
            unsigned* rw = (unsigned*)(hpk + 2 * i + 1);
            rw[1] = __float_as_uint(dis);              // byte 20 of the 32B row
        }
    }
    if (b == BINS - 1 && t == 0) nodeoff[BINS * NPB] = end;
    if (t == 0) flag[b] = fit ? 1 : 0;
    __syncthreads();

    if (!fit) return;
    // scatter back grouped by local dst (cur[] is ABSOLUTE -> write ebuf[pos])
    for (int k = t; k < n; k += blockDim.x) {
        int v = buf[k];
        int pos = atomicAdd(&cur[((unsigned)v) >> 18], 1);
        ebuf[pos] = v;
    }
}

// ---------------------------------------------------------------- init2: h = (x @ W) * dis,
// packed fp16 into 32B rows {10 fp16, fp32 dis, pad} — one cache line serves 2 rows.
__global__ void init2_kernel(const float* __restrict__ x,
                             const float* __restrict__ Wg,
                             uint4* __restrict__ hpk) {
    __shared__ float Ws[F_IN * F_HID];
    for (int t = threadIdx.x; t < F_IN * F_HID; t += blockDim.x) Ws[t] = Wg[t];
    __syncthreads();

    int i = blockIdx.x * blockDim.x + threadIdx.x;
    if (i >= N_NODES) return;

    float acc[F_HID];
#pragma unroll
    for (int f = 0; f < F_HID; ++f) acc[f] = 0.0f;

    const float* xr = x + (long long)i * F_IN;
#pragma unroll
    for (int k = 0; k < F_IN; ++k) {
        float xv = xr[k];
#pragma unroll
        for (int f = 0; f < F_HID; ++f) acc[f] += xv * Ws[k * F_HID + f];
    }

    const unsigned* rro = (const unsigned*)(hpk + 2 * i + 1);
    unsigned disbits = rro[1];                 // dis written by p5
    float di = __uint_as_float(disbits);

    unsigned pk[5];
#pragma unroll
    for (int k = 0; k < 5; ++k) {
        __half lo = __float2half(acc[2 * k] * di);
        __half hi = __float2half(acc[2 * k + 1] * di);
        pk[k] = ((unsigned)__half_as_ushort(hi) << 16) | (unsigned)__half_as_ushort(lo);
    }
    hpk[2 * i]     = make_uint4(pk[0], pk[1], pk[2], pk[3]);
    hpk[2 * i + 1] = make_uint4(pk[4], disbits, 0u, 0u);
}

// ---------------------------------------------------------------- pass 4b: per-node register
// gather-accumulate (NO atomics), 2 threads/node, batch-4, shfl_xor pair-combine.
// nt loads for ebuf, nt stores for out -> keep L2 for the hpk gather table.
__global__ void __launch_bounds__(512, 8)
p4b_acc_kernel(const int* __restrict__ ebuf,
               const int* __restrict__ nodeoff,
               const int* __restrict__ flag,
               const uint4* __restrict__ hpk,
               const float* __restrict__ b_gcn,
               const float* __restrict__ W_fc,
               const float* __restrict__ b_fc,
               float* __restrict__ out) {
    __shared__ float accs[NPB * ACCP];   // fallback arm only
    __shared__ float Wfs[F_HID * F_OUT];
    __shared__ float bfs[F_OUT];
    __shared__ float bgs[F_HID];

    int b = blockIdx.x;
    int t = threadIdx.x;                 // 0..511
    int jl = t >> 1;                     // local node 0..255
    int par = t & 1;                     // parity within node pair
    if (t < F_HID * F_OUT) Wfs[t] = W_fc[t];
    if (t < F_OUT) bfs[t] = b_fc[t];
    if (t < F_HID) bgs[t] = b_gcn[t];
    __syncthreads();

    float* hidden = out;                               // [N, F_HID]
    floatx4* o24 = reinterpret_cast<floatx4*>(out + (long long)N_NODES * F_HID);

    int i = b * NPB + jl;
    bool valid = (i < N_NODES);
    float acc[F_HID];
#pragma unroll
    for (int f = 0; f < F_HID; ++f) acc[f] = 0.0f;

    if (flag[b]) {
        // ---------- fast arm: dst-sorted, register accumulation ----------
        int rs = valid ? nodeoff[i] : 0;
        int re = valid ? nodeoff[i + 1] : 0;
        for (int k = rs + par; k < re; k += 8) {      // this thread: k, k+2, k+4, k+6
            unsigned v[4]; uint4 qa[4]; uint4 qb[4];
#pragma unroll
            for (int u = 0; u < 4; ++u)
                v[u] = (unsigned)__builtin_nontemporal_load(ebuf + min(k + 2 * u, re - 1));
#pragma unroll
            for (int u = 0; u < 4; ++u) {
                int s = v[u] & 0x3FFFF;
                qa[u] = hpk[2 * s];                   // same 64B line
                qb[u] = hpk[2 * s + 1];
            }
#pragma unroll
            for (int u = 0; u < 4; ++u) {
                if (k + 2 * u < re) {
                    float2 f01 = up2(qa[u].x), f23 = up2(qa[u].y);
                    float2 f45 = up2(qa[u].z), f67 = up2(qa[u].w);
                    float2 f89 = up2(qb[u].x);
                    acc[0] += f01.x; acc[1] += f01.y;
                    acc[2] += f23.x; acc[3] += f23.y;
                    acc[4] += f45.x; acc[5] += f45.y;
                    acc[6] += f67.x; acc[7] += f67.y;
                    acc[8] += f89.x; acc[9] += f89.y;
                }
            }
        }
    } else {
        // ---------- fallback arm: unsorted bucket, LDS atomics (never taken for valid input) ----
        for (int j = t; j < NPB * ACCP; j += blockDim.x) accs[j] = 0.0f;
        __syncthreads();
        int start = nodeoff[b * NPB];
        int end = nodeoff[(b + 1) * NPB];
        for (int e = start + t; e < end; e += blockDim.x) {
            unsigned v = (unsigned)ebuf[e];
            int s = v & 0x3FFFF;
            int ld = v >> 18;
            uint4 qa = hpk[2 * s]; uint4 qb = hpk[2 * s + 1];
            float2 f01 = up2(qa.x), f23 = up2(qa.y), f45 = up2(qa.z), f67 = up2(qa.w), f89 = up2(qb.x);
            float* a = &accs[ld * ACCP];
            atomicAdd(a + 0, f01.x); atomicAdd(a + 1, f01.y);
            atomicAdd(a + 2, f23.x); atomicAdd(a + 3, f23.y);
            atomicAdd(a + 4, f45.x); atomicAdd(a + 5, f45.y);
            atomicAdd(a + 6, f67.x); atomicAdd(a + 7, f67.y);
            atomicAdd(a + 8, f89.x); atomicAdd(a + 9, f89.y);
        }
        __syncthreads();
        if (par == 0) {
#pragma unroll
            for (int f = 0; f < F_HID; ++f) acc[f] = accs[jl * ACCP + f];
        }
    }

    // pair-combine: acc[node] = even-lane acc + odd-lane acc
#pragma unroll
    for (int f = 0; f < F_HID; ++f) acc[f] += __shfl_xor(acc[f], 1);

    if (!valid || par) return;

    uint4 qa = hpk[2 * i]; uint4 qb = hpk[2 * i + 1];
    float di = __uint_as_float(qb.y);
    float2 f01 = up2(qa.x), f23 = up2(qa.y), f45 = up2(qa.z), f67 = up2(qa.w), f89 = up2(qb.x);
    float hp[F_HID] = {f01.x, f01.y, f23.x, f23.y, f45.x, f45.y, f67.x, f67.y, f89.x, f89.y};

    float hv[F_HID];
#pragma unroll
    for (int f = 0; f < F_HID; ++f) {
        hv[f] = (acc[f] + hp[f]) * di + bgs[f];    // (sum_nbrs h' + h'[i]) * dis[i] + b
        __builtin_nontemporal_store(hv[f], hidden + (long long)i * F_HID + f);
    }
    floatx4 o;
#pragma unroll
    for (int jj = 0; jj < F_OUT; ++jj) {
        float vv = bfs[jj];
#pragma unroll
        for (int f = 0; f < F_HID; ++f) vv += hv[f] * Wfs[f * F_OUT + jj];
        o[jj] = fmaxf(vv, 0.0f);
    }
    __builtin_nontemporal_store(o, o24 + i);
}

// ================================================================ FALLBACK (atomic scatter, small ws)
__global__ void fb_init_kernel(const float* __restrict__ x, const float* __restrict__ Wg,
                               float* __restrict__ hpad, float* __restrict__ deg,
                               float* __restrict__ hidden) {
    __shared__ float Ws[F_IN * F_HID];
    for (int t = threadIdx.x; t < F_IN * F_HID; t += blockDim.x) Ws[t] = Wg[t];
    __syncthreads();
    int i = blockIdx.x * blockDim.x + threadIdx.x;
    if (i >= N_NODES) return;
    float acc[F_HID];
#pragma unroll
    for (int f = 0; f < F_HID; ++f) acc[f] = 0.0f;
    const float* xr = x + (long long)i * F_IN;
#pragma unroll
    for (int k = 0; k < F_IN; ++k) {
        float xv = xr[k];
#pragma unroll
        for (int f = 0; f < F_HID; ++f) acc[f] += xv * Ws[k * F_HID + f];
    }
    float* hr = hpad + (long long)i * HPAD;
#pragma unroll
    for (int f = 0; f < F_HID; ++f) hr[f] = acc[f];
    hr[10] = 0.0f; hr[11] = 0.0f;
    deg[i] = 1.0f;
    float* hd = hidden + (long long)i * F_HID;
#pragma unroll
    for (int f = 0; f < F_HID; ++f) hd[f] = 0.0f;
}

__global__ void fb_deg_kernel(const int* __restrict__ ei, const int* __restrict__ mode_p,
                              float* __restrict__ deg) {
    const int mode = *mode_p;
    long long e = (long long)blockIdx.x * blockDim.x + threadIdx.x;
    if (e >= N_EDGES) return;
    int d = load_idx(ei, (long long)N_EDGES + e, mode);
    if ((unsigned)d < (unsigned)N_NODES) atomicAdd(&deg[d], 1.0f);
}

__global__ void fb_scatter_kernel(const int* __restrict__ ei, const int* __restrict__ mode_p,
                                  const float* __restrict__ hpad, const float* __restrict__ deg,
                                  float* __restrict__ hidden) {
    const int mode = *mode_p;
    long long e = (long long)blockIdx.x * blockDim.x + threadIdx.x;
    if (e >= N_EDGES) return;
    int s = load_idx(ei, e, mode);
    int d = load_idx(ei, (long long)N_EDGES + e, mode);
    if ((unsigned)s >= (unsigned)N_NODES || (unsigned)d >= (unsigned)N_NODES) return;
    float norm = rsqrtf(deg[s]) * rsqrtf(deg[d]);
    const float4* h4 = reinterpret_cast<const float4*>(hpad + (long long)s * HPAD);
    float4 a = h4[0]; float4 b = h4[1]; float4 c = h4[2];
    float* o = hidden + (long long)d * F_HID;
    atomicAdd(o + 0, a.x * norm); atomicAdd(o + 1, a.y * norm);
    atomicAdd(o + 2, a.z * norm); atomicAdd(o + 3, a.w * norm);
    atomicAdd(o + 4, b.x * norm); atomicAdd(o + 5, b.y * norm);
    atomicAdd(o + 6, b.z * norm); atomicAdd(o + 7, b.w * norm);
    atomicAdd(o + 8, c.x * norm); atomicAdd(o + 9, c.y * norm);
}

__global__ void fb_finalize_kernel(const float* __restrict__ hpad, const float* __restrict__ deg,
                                   const float* __restrict__ b_gcn, const float* __restrict__ W_fc,
                                   const float* __restrict__ b_fc, float* __restrict__ out) {
    __shared__ float Wf[F_HID * F_OUT];
    __shared__ float bf_s[F_OUT];
    __shared__ float bg_s[F_HID];
    for (int t = threadIdx.x; t < F_HID * F_OUT; t += blockDim.x) Wf[t] = W_fc[t];
    if (threadIdx.x < F_OUT) bf_s[threadIdx.x] = b_fc[threadIdx.x];
    if (threadIdx.x < F_HID) bg_s[threadIdx.x] = b_gcn[threadIdx.x];
    __syncthreads();
    int i = blockIdx.x * blockDim.x + threadIdx.x;
    if (i >= N_NODES) return;
    float* hidden = out;
    float* o2 = out + (long long)N_NODES * F_HID;
    float inv = 1.0f / deg[i];
    const float* hr = hpad + (long long)i * HPAD;
    float* hd = hidden + (long long)i * F_HID;
    float hv[F_HID];
#pragma unroll
    for (int f = 0; f < F_HID; ++f) {
        hv[f] = hd[f] + hr[f] * inv + bg_s[f];
        hd[f] = hv[f];
    }
#pragma unroll
    for (int j = 0; j < F_OUT; ++j) {
        float o = bf_s[j];
#pragma unroll
        for (int f = 0; f < F_HID; ++f) o += hv[f] * Wf[f * F_OUT + j];
        o2[(long long)i * F_OUT + j] = fmaxf(o, 0.0f);
    }
}

// ---------------------------------------------------------------- launch
extern "C" void kernel_launch(void* const* d_in, const int* in_sizes, int n_in,
                              void* d_out, int out_size, void* d_ws, size_t ws_size,
                              hipStream_t stream) {
    const float* x  = (const float*)d_in[0];
    const int*   ei = (const int*)d_in[1];
    const float* Wg = (const float*)d_in[2];
    const float* bg = (const float*)d_in[3];
    const float* Wf = (const float*)d_in[4];
    const float* bf = (const float*)d_in[5];
    float* out = (float*)d_out;

    const int nblk_node = (N_NODES + 255) / 256;     // 782

    // main ws layout (~36.1 MB)
    uint4* hpk     = (uint4*)d_ws;                              // 2*(BINS*NPB) uint4 = 6.4MB
    int*   bcnt    = (int*)(hpk + 2 * (size_t)BINS * NPB);      // SCAN_L
    int*   boff    = bcnt + SCAN_L;                             // SCAN_L
    int*   bsum    = boff + SCAN_L;                             // 1024 (NA=796 used)
    int*   total   = bsum + 1024;                               // 1
    int*   nodeoff = total + 1;                                 // BINS*NPB+1
    int*   flag    = nodeoff + BINS * NPB + 1;                  // BINS
    int*   ebuf    = flag + BINS;                               // N_EDGES
    int*   mode    = ebuf + N_EDGES;                            // 1
    size_t need = (size_t)((char*)(mode + 1) - (char*)d_ws);

    if (ws_size >= need) {
        detect_mode_kernel<<<1, 64, 0, stream>>>(ei, mode);
        p1_count_kernel<<<BLK1, 512, 0, stream>>>(ei, mode, bcnt);
        scanA_kernel<<<NA, 512, 0, stream>>>(bcnt, bsum);
        scanB_kernel<<<1, 1024, 0, stream>>>(bsum, total);
        scanC_kernel<<<NA, 512, 0, stream>>>(bcnt, bsum, boff);
        p3_fill_kernel<<<BLK1, 512, 0, stream>>>(ei, mode, boff, ebuf);
        p5_sort_kernel<<<BINS, 512, 0, stream>>>(ebuf, boff, total, hpk, nodeoff, flag);
        init2_kernel<<<nblk_node, 256, 0, stream>>>(x, Wg, hpk);
        p4b_acc_kernel<<<BINS, 512, 0, stream>>>(ebuf, nodeoff, flag, hpk,
                                                 bg, Wf, bf, out);
    } else {
        // fallback: atomic scatter (~10.4 MB)
        float* hpad  = (float*)d_ws;
        float* degf  = hpad + (size_t)N_NODES * HPAD;
        int*   mode2 = (int*)(degf + N_NODES);
        const int nblk_edge = (N_EDGES + 255) / 256;
        detect_mode_kernel<<<1, 64, 0, stream>>>(ei, mode2);
        fb_init_kernel<<<nblk_node, 256, 0, stream>>>(x, Wg, hpad, degf, out);
        fb_deg_kernel<<<nblk_edge, 256, 0, stream>>>(ei, mode2, degf);
        fb_scatter_kernel<<<nblk_edge, 256, 0, stream>>>(ei, mode2, hpad, degf, out);
        fb_finalize_kernel<<<nblk_node, 256, 0, stream>>>(hpad, degf, bg, Wf, bf, out);
    }
}

// Round 11
// 295.620 us; speedup vs baseline: 1.2209x; 1.2209x over previous
//
#include <hip/hip_runtime.h>
#include <hip/hip_fp16.h>

#define N_NODES 200000
#define N_EDGES 6400000
#define F_IN 34
#define F_HID 10
#define F_OUT 4
#define HPAD 12              // fb path only: 48B fp32 rows
#define BINS 782             // dst buckets
#define NPB 256              // nodes per bucket: 782*256 = 200192 >= N
#define CHUNK 16384
#define BLK1 ((N_EDGES + CHUNK - 1) / CHUNK)    // 391
#define SCAN_L (BINS * BLK1)                    // 305762
#define NA ((SCAN_L + 511) / 512)               // 598 (<= 1024 for scanB)
#define ACCP 11              // fallback-arm LDS acc padding
#define SORT_CAP 12288       // 48KB LDS in p5; bucket avg 8184, sigma~90

typedef float floatx4 __attribute__((ext_vector_type(4)));   // nontemporal-store-compatible

// ---------------------------------------------------------------- helpers
__device__ __forceinline__ float2 up2(unsigned u) {
    __half2 h = *reinterpret_cast<const __half2*>(&u);
    return __half22float2(h);
}

// ---------------------------------------------------------------- mode detect
// int64 edge_index => every odd 32-bit word is zero (values < 2^31).
__global__ void detect_mode_kernel(const int* __restrict__ ei, int* __restrict__ mode) {
    int t = threadIdx.x;                 // 64 threads
    int v = ei[2 * t + 1];
    unsigned long long b = __ballot(v != 0);
    if (t == 0) *mode = (b == 0ull) ? 1 : 0;
}

__device__ __forceinline__ int load_idx(const int* ei, long long elem, int mode) {
    return mode ? ei[2 * elem] : ei[elem];
}

// ---------------------------------------------------------------- pass 1: bucket counts (LDS hist)
__global__ void p1_count_kernel(const int* __restrict__ ei,
                                const int* __restrict__ mode_p,
                                int* __restrict__ bcnt) {
    __shared__ int hist[BINS];
    const int mode = *mode_p;
    int t = threadIdx.x;
    for (int j = t; j < BINS; j += blockDim.x) hist[j] = 0;
    __syncthreads();

    long long base = (long long)blockIdx.x * CHUNK;
    for (int k = t; k < CHUNK; k += blockDim.x) {
        long long e = base + k;
        if (e >= N_EDGES) break;
        int d = load_idx(ei, (long long)N_EDGES + e, mode);
        if ((unsigned)d < (unsigned)N_NODES) atomicAdd(&hist[d >> 8], 1);
    }
    __syncthreads();
    for (int j = t; j < BINS; j += blockDim.x)
        bcnt[j * BLK1 + blockIdx.x] = hist[j];   // bin-major
}

// ---------------------------------------------------------------- scan A: per-512-block sums
__global__ void scanA_kernel(const int* __restrict__ src, int* __restrict__ bsum) {
    __shared__ int s[512];
    int t = threadIdx.x;
    int i = blockIdx.x * 512 + t;
    s[t] = (i < SCAN_L) ? src[i] : 0;
    __syncthreads();
    for (int o = 256; o > 0; o >>= 1) {
        if (t < o) s[t] += s[t + o];
        __syncthreads();
    }
    if (t == 0) bsum[blockIdx.x] = s[0];
}

// ---------------------------------------------------------------- scan B: exclusive scan of NA block sums
__global__ void scanB_kernel(int* __restrict__ bsum, int* __restrict__ total) {
    __shared__ int s[1024];
    int t = threadIdx.x;
    int v = (t < NA) ? bsum[t] : 0;
    s[t] = v;
    __syncthreads();
    for (int o = 1; o < 1024; o <<= 1) {
        int u = (t >= o) ? s[t - o] : 0;
        __syncthreads();
        s[t] += u;
        __syncthreads();
    }
    if (t < NA) bsum[t] = s[t] - v;             // exclusive block offset
    if (t == 1023) *total = s[t];
}

// ---------------------------------------------------------------- scan C: produce boff (512-granule)
__global__ void scanC_kernel(const int* __restrict__ src,
                             const int* __restrict__ bsum,
                             int* __restrict__ dst) {
    __shared__ int s[512];
    int t = threadIdx.x;
    int i = blockIdx.x * 512 + t;
    int v = (i < SCAN_L) ? src[i] : 0;
    s[t] = v;
    __syncthreads();
    for (int o = 1; o < 512; o <<= 1) {
        int u = (t >= o) ? s[t - o] : 0;
        __syncthreads();
        s[t] += u;
        __syncthreads();
    }
    if (i < SCAN_L) dst[i] = bsum[blockIdx.x] + s[t] - v;  // exclusive prefix
}

// ---------------------------------------------------------------- pass 3: LDS-staged fill.
// Load per-block hist from bcnt, wave-scan to local offsets, place edges into LDS buf at
// sorted local positions, then write each bin's run to ebuf as a coalesced burst.
__global__ void __launch_bounds__(512, 4)
p3_fill_kernel(const int* __restrict__ ei,
               const int* __restrict__ mode_p,
               const int* __restrict__ bcnt,
               const int* __restrict__ boff,
               int* __restrict__ ebuf) {
    __shared__ int buf[CHUNK];          // 64 KB
    __shared__ int hist[BINS];
    __shared__ int lstart[BINS];
    __shared__ int cur[BINS];

    const int mode = *mode_p;
    int t = threadIdx.x;
    int blk = blockIdx.x;

    for (int j = t; j < BINS; j += 512) hist[j] = bcnt[j * BLK1 + blk];
    __syncthreads();

    // exclusive scan of hist[0..BINS) by wave 0: 13 bins/lane (64*13=832 >= 782)
    if (t < 64) {
        int base = t * 13;
        int run = 0;
        int loc[13];
#pragma unroll
        for (int u = 0; u < 13; ++u) {
            int idx = base + u;
            int v = (idx < BINS) ? hist[idx] : 0;
            loc[u] = run;
            run += v;
        }
        int inc = run;
        for (int o = 1; o < 64; o <<= 1) {
            int up = __shfl_up(inc, o);
            if (t >= o) inc += up;
        }
        int excl = inc - run;
#pragma unroll
        for (int u = 0; u < 13; ++u) {
            int idx = base + u;
            if (idx < BINS) { lstart[idx] = excl + loc[u]; cur[idx] = excl + loc[u]; }
        }
    }
    __syncthreads();

    // pass B: read edges, place into buf at sorted local position
    long long base = (long long)blk * CHUNK;
    int nthis = (int)(((long long)N_EDGES - base < (long long)CHUNK)
                      ? ((long long)N_EDGES - base) : (long long)CHUNK);
    for (int k = t; k < nthis; k += 512) {
        long long e = base + k;
        int d = load_idx(ei, (long long)N_EDGES + e, mode);
        if ((unsigned)d >= (unsigned)N_NODES) continue;
        int s = load_idx(ei, e, mode);
        s = min(max(s, 0), N_NODES - 1);         // memory-safety clamp (input always valid)
        int bin = d >> 8;
        int ld = d & 255;
        int pos = atomicAdd(&cur[bin], 1);       // local position in sorted order
        buf[pos] = s | (ld << 18);               // src:18 bits | local_dst:8 bits
    }
    __syncthreads();

    // write-out: wave w handles bins w, w+8, ... — contiguous coalesced bursts
    int wave = t >> 6, lane = t & 63;
    for (int bb = wave; bb < BINS; bb += 8) {
        int ls = lstart[bb];
        int ncnt = cur[bb] - ls;
        int gb = boff[bb * BLK1 + blk];
        for (int k = lane; k < ncnt; k += 64)
            ebuf[gb + k] = buf[ls + k];
    }
}

// ---------------------------------------------------------------- pass 5: per-bucket counting
// sort by LOCAL DST (LDS, in-place in ebuf) -> dst-sorted edges + nodeoff + per-node dis
// written into the 32B hpk row (byte 20). flag[b] records sortedness for p4b's fast arm.
__global__ void p5_sort_kernel(int* __restrict__ ebuf,
                               const int* __restrict__ boff,
                               const int* __restrict__ total,
                               uint4* __restrict__ hpk,
                               int* __restrict__ nodeoff,
                               int* __restrict__ flag) {
    __shared__ int buf[SORT_CAP];
    __shared__ int cnt[NPB];
    __shared__ int sc[NPB];
    __shared__ int cur[NPB];

    int b = blockIdx.x;
    int t = threadIdx.x;
    if (t < NPB) cnt[t] = 0;
    __syncthreads();

    int start = boff[b * BLK1];
    int end = (b < BINS - 1) ? boff[(b + 1) * BLK1] : *total;
    int n = end - start;
    bool fit = (n <= SORT_CAP);

    for (int k = t; k < n; k += blockDim.x) {
        int v = ebuf[start + k];
        atomicAdd(&cnt[((unsigned)v) >> 18], 1);
        if (fit) buf[k] = v;
    }
    __syncthreads();

    // exclusive scan of cnt (256 entries, threads t<256)
    if (t < NPB) sc[t] = cnt[t];
    __syncthreads();
    for (int o = 1; o < NPB; o <<= 1) {
        int u = (t < NPB && t >= o) ? sc[t - o] : 0;
        __syncthreads();
        if (t < NPB) sc[t] += u;
        __syncthreads();
    }
    if (t < NPB) {
        int excl = sc[t] - cnt[t];
        nodeoff[b * NPB + t] = start + excl;
        cur[t] = start + excl;               // ABSOLUTE cursor
        int i = b * NPB + t;
        if (i < N_NODES) {
            float dis = rsqrtf((float)(cnt[t] + 1));   // +1 self-loop
            unsigned* rw = (unsigned*)(hpk + 2 * i + 1);
            rw[1] = __float_as_uint(dis);              // byte 20 of the 32B row
        }
    }
    if (b == BINS - 1 && t == 0) nodeoff[BINS * NPB] = end;
    if (t == 0) flag[b] = fit ? 1 : 0;
    __syncthreads();

    if (!fit) return;
    // scatter back grouped by local dst (cur[] is ABSOLUTE -> write ebuf[pos])
    for (int k = t; k < n; k += blockDim.x) {
        int v = buf[k];
        int pos = atomicAdd(&cur[((unsigned)v) >> 18], 1);
        ebuf[pos] = v;
    }
}

// ---------------------------------------------------------------- init2: h = (x @ W) * dis,
// packed fp16 into 32B rows {10 fp16, fp32 dis, pad} — one cache line serves 2 rows.
__global__ void init2_kernel(const float* __restrict__ x,
                             const float* __restrict__ Wg,
                             uint4* __restrict__ hpk) {
    __shared__ float Ws[F_IN * F_HID];
    for (int t = threadIdx.x; t < F_IN * F_HID; t += blockDim.x) Ws[t] = Wg[t];
    __syncthreads();

    int i = blockIdx.x * blockDim.x + threadIdx.x;
    if (i >= N_NODES) return;

    float acc[F_HID];
#pragma unroll
    for (int f = 0; f < F_HID; ++f) acc[f] = 0.0f;

    const float* xr = x + (long long)i * F_IN;
#pragma unroll
    for (int k = 0; k < F_IN; ++k) {
        float xv = xr[k];
#pragma unroll
        for (int f = 0; f < F_HID; ++f) acc[f] += xv * Ws[k * F_HID + f];
    }

    const unsigned* rro = (const unsigned*)(hpk + 2 * i + 1);
    unsigned disbits = rro[1];                 // dis written by p5
    float di = __uint_as_float(disbits);

    unsigned pk[5];
#pragma unroll
    for (int k = 0; k < 5; ++k) {
        __half lo = __float2half(acc[2 * k] * di);
        __half hi = __float2half(acc[2 * k + 1] * di);
        pk[k] = ((unsigned)__half_as_ushort(hi) << 16) | (unsigned)__half_as_ushort(lo);
    }
    hpk[2 * i]     = make_uint4(pk[0], pk[1], pk[2], pk[3]);
    hpk[2 * i + 1] = make_uint4(pk[4], disbits, 0u, 0u);
}

// ---------------------------------------------------------------- pass 4b: per-node register
// gather-accumulate (NO atomics), 2 threads/node, batch-4, shfl_xor pair-combine.
// nt loads for ebuf, nt stores for out -> keep L2 for the hpk gather table.
__global__ void __launch_bounds__(512, 8)
p4b_acc_kernel(const int* __restrict__ ebuf,
               const int* __restrict__ nodeoff,
               const int* __restrict__ flag,
               const uint4* __restrict__ hpk,
               const float* __restrict__ b_gcn,
               const float* __restrict__ W_fc,
               const float* __restrict__ b_fc,
               float* __restrict__ out) {
    __shared__ float accs[NPB * ACCP];   // fallback arm only
    __shared__ float Wfs[F_HID * F_OUT];
    __shared__ float bfs[F_OUT];
    __shared__ float bgs[F_HID];

    int b = blockIdx.x;
    int t = threadIdx.x;                 // 0..511
    int jl = t >> 1;                     // local node 0..255
    int par = t & 1;                     // parity within node pair
    if (t < F_HID * F_OUT) Wfs[t] = W_fc[t];
    if (t < F_OUT) bfs[t] = b_fc[t];
    if (t < F_HID) bgs[t] = b_gcn[t];
    __syncthreads();

    float* hidden = out;                               // [N, F_HID]
    floatx4* o24 = reinterpret_cast<floatx4*>(out + (long long)N_NODES * F_HID);

    int i = b * NPB + jl;
    bool valid = (i < N_NODES);
    float acc[F_HID];
#pragma unroll
    for (int f = 0; f < F_HID; ++f) acc[f] = 0.0f;

    if (flag[b]) {
        // ---------- fast arm: dst-sorted, register accumulation ----------
        int rs = valid ? nodeoff[i] : 0;
        int re = valid ? nodeoff[i + 1] : 0;
        for (int k = rs + par; k < re; k += 8) {      // this thread: k, k+2, k+4, k+6
            unsigned v[4]; uint4 qa[4]; uint4 qb[4];
#pragma unroll
            for (int u = 0; u < 4; ++u)
                v[u] = (unsigned)__builtin_nontemporal_load(ebuf + min(k + 2 * u, re - 1));
#pragma unroll
            for (int u = 0; u < 4; ++u) {
                int s = v[u] & 0x3FFFF;
                qa[u] = hpk[2 * s];                   // same 64B line
                qb[u] = hpk[2 * s + 1];
            }
#pragma unroll
            for (int u = 0; u < 4; ++u) {
                if (k + 2 * u < re) {
                    float2 f01 = up2(qa[u].x), f23 = up2(qa[u].y);
                    float2 f45 = up2(qa[u].z), f67 = up2(qa[u].w);
                    float2 f89 = up2(qb[u].x);
                    acc[0] += f01.x; acc[1] += f01.y;
                    acc[2] += f23.x; acc[3] += f23.y;
                    acc[4] += f45.x; acc[5] += f45.y;
                    acc[6] += f67.x; acc[7] += f67.y;
                    acc[8] += f89.x; acc[9] += f89.y;
                }
            }
        }
    } else {
        // ---------- fallback arm: unsorted bucket, LDS atomics (never taken for valid input) ----
        for (int j = t; j < NPB * ACCP; j += blockDim.x) accs[j] = 0.0f;
        __syncthreads();
        int start = nodeoff[b * NPB];
        int end = nodeoff[(b + 1) * NPB];
        for (int e = start + t; e < end; e += blockDim.x) {
            unsigned v = (unsigned)ebuf[e];
            int s = v & 0x3FFFF;
            int ld = v >> 18;
            uint4 qa = hpk[2 * s]; uint4 qb = hpk[2 * s + 1];
            float2 f01 = up2(qa.x), f23 = up2(qa.y), f45 = up2(qa.z), f67 = up2(qa.w), f89 = up2(qb.x);
            float* a = &accs[ld * ACCP];
            atomicAdd(a + 0, f01.x); atomicAdd(a + 1, f01.y);
            atomicAdd(a + 2, f23.x); atomicAdd(a + 3, f23.y);
            atomicAdd(a + 4, f45.x); atomicAdd(a + 5, f45.y);
            atomicAdd(a + 6, f67.x); atomicAdd(a + 7, f67.y);
            atomicAdd(a + 8, f89.x); atomicAdd(a + 9, f89.y);
        }
        __syncthreads();
        if (par == 0) {
#pragma unroll
            for (int f = 0; f < F_HID; ++f) acc[f] = accs[jl * ACCP + f];
        }
    }

    // pair-combine: acc[node] = even-lane acc + odd-lane acc
#pragma unroll
    for (int f = 0; f < F_HID; ++f) acc[f] += __shfl_xor(acc[f], 1);

    if (!valid || par) return;

    uint4 qa = hpk[2 * i]; uint4 qb = hpk[2 * i + 1];
    float di = __uint_as_float(qb.y);
    float2 f01 = up2(qa.x), f23 = up2(qa.y), f45 = up2(qa.z), f67 = up2(qa.w), f89 = up2(qb.x);
    float hp[F_HID] = {f01.x, f01.y, f23.x, f23.y, f45.x, f45.y, f67.x, f67.y, f89.x, f89.y};

    float hv[F_HID];
#pragma unroll
    for (int f = 0; f < F_HID; ++f) {
        hv[f] = (acc[f] + hp[f]) * di + bgs[f];    // (sum_nbrs h' + h'[i]) * dis[i] + b
        __builtin_nontemporal_store(hv[f], hidden + (long long)i * F_HID + f);
    }
    floatx4 o;
#pragma unroll
    for (int jj = 0; jj < F_OUT; ++jj) {
        float vv = bfs[jj];
#pragma unroll
        for (int f = 0; f < F_HID; ++f) vv += hv[f] * Wfs[f * F_OUT + jj];
        o[jj] = fmaxf(vv, 0.0f);
    }
    __builtin_nontemporal_store(o, o24 + i);
}

// ================================================================ FALLBACK (atomic scatter, small ws)
__global__ void fb_init_kernel(const float* __restrict__ x, const float* __restrict__ Wg,
                               float* __restrict__ hpad, float* __restrict__ deg,
                               float* __restrict__ hidden) {
    __shared__ float Ws[F_IN * F_HID];
    for (int t = threadIdx.x; t < F_IN * F_HID; t += blockDim.x) Ws[t] = Wg[t];
    __syncthreads();
    int i = blockIdx.x * blockDim.x + threadIdx.x;
    if (i >= N_NODES) return;
    float acc[F_HID];
#pragma unroll
    for (int f = 0; f < F_HID; ++f) acc[f] = 0.0f;
    const float* xr = x + (long long)i * F_IN;
#pragma unroll
    for (int k = 0; k < F_IN; ++k) {
        float xv = xr[k];
#pragma unroll
        for (int f = 0; f < F_HID; ++f) acc[f] += xv * Ws[k * F_HID + f];
    }
    float* hr = hpad + (long long)i * HPAD;
#pragma unroll
    for (int f = 0; f < F_HID; ++f) hr[f] = acc[f];
    hr[10] = 0.0f; hr[11] = 0.0f;
    deg[i] = 1.0f;
    float* hd = hidden + (long long)i * F_HID;
#pragma unroll
    for (int f = 0; f < F_HID; ++f) hd[f] = 0.0f;
}

__global__ void fb_deg_kernel(const int* __restrict__ ei, const int* __restrict__ mode_p,
                              float* __restrict__ deg) {
    const int mode = *mode_p;
    long long e = (long long)blockIdx.x * blockDim.x + threadIdx.x;
    if (e >= N_EDGES) return;
    int d = load_idx(ei, (long long)N_EDGES + e, mode);
    if ((unsigned)d < (unsigned)N_NODES) atomicAdd(&deg[d], 1.0f);
}

__global__ void fb_scatter_kernel(const int* __restrict__ ei, const int* __restrict__ mode_p,
                                  const float* __restrict__ hpad, const float* __restrict__ deg,
                                  float* __restrict__ hidden) {
    const int mode = *mode_p;
    long long e = (long long)blockIdx.x * blockDim.x + threadIdx.x;
    if (e >= N_EDGES) return;
    int s = load_idx(ei, e, mode);
    int d = load_idx(ei, (long long)N_EDGES + e, mode);
    if ((unsigned)s >= (unsigned)N_NODES || (unsigned)d >= (unsigned)N_NODES) return;
    float norm = rsqrtf(deg[s]) * rsqrtf(deg[d]);
    const float4* h4 = reinterpret_cast<const float4*>(hpad + (long long)s * HPAD);
    float4 a = h4[0]; float4 b = h4[1]; float4 c = h4[2];
    float* o = hidden + (long long)d * F_HID;
    atomicAdd(o + 0, a.x * norm); atomicAdd(o + 1, a.y * norm);
    atomicAdd(o + 2, a.z * norm); atomicAdd(o + 3, a.w * norm);
    atomicAdd(o + 4, b.x * norm); atomicAdd(o + 5, b.y * norm);
    atomicAdd(o + 6, b.z * norm); atomicAdd(o + 7, b.w * norm);
    atomicAdd(o + 8, c.x * norm); atomicAdd(o + 9, c.y * norm);
}

__global__ void fb_finalize_kernel(const float* __restrict__ hpad, const float* __restrict__ deg,
                                   const float* __restrict__ b_gcn, const float* __restrict__ W_fc,
                                   const float* __restrict__ b_fc, float* __restrict__ out) {
    __shared__ float Wf[F_HID * F_OUT];
    __shared__ float bf_s[F_OUT];
    __shared__ float bg_s[F_HID];
    for (int t = threadIdx.x; t < F_HID * F_OUT; t += blockDim.x) Wf[t] = W_fc[t];
    if (threadIdx.x < F_OUT) bf_s[threadIdx.x] = b_fc[threadIdx.x];
    if (threadIdx.x < F_HID) bg_s[threadIdx.x] = b_gcn[threadIdx.x];
    __syncthreads();
    int i = blockIdx.x * blockDim.x + threadIdx.x;
    if (i >= N_NODES) return;
    float* hidden = out;
    float* o2 = out + (long long)N_NODES * F_HID;
    float inv = 1.0f / deg[i];
    const float* hr = hpad + (long long)i * HPAD;
    float* hd = hidden + (long long)i * F_HID;
    float hv[F_HID];
#pragma unroll
    for (int f = 0; f < F_HID; ++f) {
        hv[f] = hd[f] + hr[f] * inv + bg_s[f];
        hd[f] = hv[f];
    }
#pragma unroll
    for (int j = 0; j < F_OUT; ++j) {
        float o = bf_s[j];
#pragma unroll
        for (int f = 0; f < F_HID; ++f) o += hv[f] * Wf[f * F_OUT + j];
        o2[(long long)i * F_OUT + j] = fmaxf(o, 0.0f);
    }
}

// ---------------------------------------------------------------- launch
extern "C" void kernel_launch(void* const* d_in, const int* in_sizes, int n_in,
                              void* d_out, int out_size, void* d_ws, size_t ws_size,
                              hipStream_t stream) {
    const float* x  = (const float*)d_in[0];
    const int*   ei = (const int*)d_in[1];
    const float* Wg = (const float*)d_in[2];
    const float* bg = (const float*)d_in[3];
    const float* Wf = (const float*)d_in[4];
    const float* bf = (const float*)d_in[5];
    float* out = (float*)d_out;

    const int nblk_node = (N_NODES + 255) / 256;     // 782

    // main ws layout (~35.3 MB)
    uint4* hpk     = (uint4*)d_ws;                              // 2*(BINS*NPB) uint4 = 6.4MB
    int*   bcnt    = (int*)(hpk + 2 * (size_t)BINS * NPB);      // SCAN_L
    int*   boff    = bcnt + SCAN_L;                             // SCAN_L
    int*   bsum    = boff + SCAN_L;                             // 1024 (NA=598 used)
    int*   total   = bsum + 1024;                               // 1
    int*   nodeoff = total + 1;                                 // BINS*NPB+1
    int*   flag    = nodeoff + BINS * NPB + 1;                  // BINS
    int*   ebuf    = flag + BINS;                               // N_EDGES
    int*   mode    = ebuf + N_EDGES;                            // 1
    size_t need = (size_t)((char*)(mode + 1) - (char*)d_ws);

    if (ws_size >= need) {
        detect_mode_kernel<<<1, 64, 0, stream>>>(ei, mode);
        p1_count_kernel<<<BLK1, 512, 0, stream>>>(ei, mode, bcnt);
        scanA_kernel<<<NA, 512, 0, stream>>>(bcnt, bsum);
        scanB_kernel<<<1, 1024, 0, stream>>>(bsum, total);
        scanC_kernel<<<NA, 512, 0, stream>>>(bcnt, bsum, boff);
        p3_fill_kernel<<<BLK1, 512, 0, stream>>>(ei, mode, bcnt, boff, ebuf);
        p5_sort_kernel<<<BINS, 512, 0, stream>>>(ebuf, boff, total, hpk, nodeoff, flag);
        init2_kernel<<<nblk_node, 256, 0, stream>>>(x, Wg, hpk);
        p4b_acc_kernel<<<BINS, 512, 0, stream>>>(ebuf, nodeoff, flag, hpk,
                                                 bg, Wf, bf, out);
    } else {
        // fallback: atomic scatter (~10.4 MB)
        float* hpad  = (float*)d_ws;
        float* degf  = hpad + (size_t)N_NODES * HPAD;
        int*   mode2 = (int*)(degf + N_NODES);
        const int nblk_edge = (N_EDGES + 255) / 256;
        detect_mode_kernel<<<1, 64, 0, stream>>>(ei, mode2);
        fb_init_kernel<<<nblk_node, 256, 0, stream>>>(x, Wg, hpad, degf, out);
        fb_deg_kernel<<<nblk_edge, 256, 0, stream>>>(ei, mode2, degf);
        fb_scatter_kernel<<<nblk_edge, 256, 0, stream>>>(ei, mode2, hpad, degf, out);
        fb_finalize_kernel<<<nblk_node, 256, 0, stream>>>(hpad, degf, bg, Wf, bf, out);
    }
}

// Round 12
// 256.520 us; speedup vs baseline: 1.4070x; 1.1524x over previous
//
#include <hip/hip_runtime.h>
#include <hip/hip_fp16.h>

#define N_NODES 200000
#define N_EDGES 6400000
#define F_IN 34
#define F_HID 10
#define F_OUT 4
#define HPAD 12              // fb path only: 48B fp32 rows
#define BINS 782             // dst buckets
#define NPB 256              // nodes per bucket: 782*256 = 200192 >= N
#define CHUNK 16384
#define BLK1 ((N_EDGES + CHUNK - 1) / CHUNK)    // 391
#define SCAN_L (BINS * BLK1)                    // 305762
#define NA ((SCAN_L + 511) / 512)               // 598 (<= 1024 for scanB)
#define ACCP 11              // fallback-arm LDS acc padding
#define SORT_CAP 12288       // 48KB LDS in p5; bucket avg 8184, sigma~90
#define SBINS 4096           // p5 composite key: (ld<<4) | (src>>14)

typedef float floatx4 __attribute__((ext_vector_type(4)));   // nontemporal-store-compatible

// ---------------------------------------------------------------- helpers
__device__ __forceinline__ float2 up2(unsigned u) {
    __half2 h = *reinterpret_cast<const __half2*>(&u);
    return __half22float2(h);
}

// ---------------------------------------------------------------- mode detect
// int64 edge_index => every odd 32-bit word is zero (values < 2^31).
__global__ void detect_mode_kernel(const int* __restrict__ ei, int* __restrict__ mode) {
    int t = threadIdx.x;                 // 64 threads
    int v = ei[2 * t + 1];
    unsigned long long b = __ballot(v != 0);
    if (t == 0) *mode = (b == 0ull) ? 1 : 0;
}

__device__ __forceinline__ int load_idx(const int* ei, long long elem, int mode) {
    return mode ? ei[2 * elem] : ei[elem];
}

// ---------------------------------------------------------------- pass 1: bucket counts (LDS hist)
__global__ void p1_count_kernel(const int* __restrict__ ei,
                                const int* __restrict__ mode_p,
                                int* __restrict__ bcnt) {
    __shared__ int hist[BINS];
    const int mode = *mode_p;
    int t = threadIdx.x;
    for (int j = t; j < BINS; j += blockDim.x) hist[j] = 0;
    __syncthreads();

    long long base = (long long)blockIdx.x * CHUNK;
    for (int k = t; k < CHUNK; k += blockDim.x) {
        long long e = base + k;
        if (e >= N_EDGES) break;
        int d = load_idx(ei, (long long)N_EDGES + e, mode);
        if ((unsigned)d < (unsigned)N_NODES) atomicAdd(&hist[d >> 8], 1);
    }
    __syncthreads();
    for (int j = t; j < BINS; j += blockDim.x)
        bcnt[j * BLK1 + blockIdx.x] = hist[j];   // bin-major
}

// ---------------------------------------------------------------- scan A: per-512-block sums
__global__ void scanA_kernel(const int* __restrict__ src, int* __restrict__ bsum) {
    __shared__ int s[512];
    int t = threadIdx.x;
    int i = blockIdx.x * 512 + t;
    s[t] = (i < SCAN_L) ? src[i] : 0;
    __syncthreads();
    for (int o = 256; o > 0; o >>= 1) {
        if (t < o) s[t] += s[t + o];
        __syncthreads();
    }
    if (t == 0) bsum[blockIdx.x] = s[0];
}

// ---------------------------------------------------------------- scan B: exclusive scan of NA block sums
__global__ void scanB_kernel(int* __restrict__ bsum, int* __restrict__ total) {
    __shared__ int s[1024];
    int t = threadIdx.x;
    int v = (t < NA) ? bsum[t] : 0;
    s[t] = v;
    __syncthreads();
    for (int o = 1; o < 1024; o <<= 1) {
        int u = (t >= o) ? s[t - o] : 0;
        __syncthreads();
        s[t] += u;
        __syncthreads();
    }
    if (t < NA) bsum[t] = s[t] - v;             // exclusive block offset
    if (t == 1023) *total = s[t];
}

// ---------------------------------------------------------------- scan C: produce boff (512-granule)
__global__ void scanC_kernel(const int* __restrict__ src,
                             const int* __restrict__ bsum,
                             int* __restrict__ dst) {
    __shared__ int s[512];
    int t = threadIdx.x;
    int i = blockIdx.x * 512 + t;
    int v = (i < SCAN_L) ? src[i] : 0;
    s[t] = v;
    __syncthreads();
    for (int o = 1; o < 512; o <<= 1) {
        int u = (t >= o) ? s[t - o] : 0;
        __syncthreads();
        s[t] += u;
        __syncthreads();
    }
    if (i < SCAN_L) dst[i] = bsum[blockIdx.x] + s[t] - v;  // exclusive prefix
}

// ---------------------------------------------------------------- pass 3: LDS-staged fill.
// Load per-block hist from bcnt, wave-scan to local offsets, place edges into LDS buf at
// sorted local positions, then write each bin's run to ebuf as a coalesced burst.
__global__ void __launch_bounds__(512, 4)
p3_fill_kernel(const int* __restrict__ ei,
               const int* __restrict__ mode_p,
               const int* __restrict__ bcnt,
               const int* __restrict__ boff,
               int* __restrict__ ebuf) {
    __shared__ int buf[CHUNK];          // 64 KB
    __shared__ int hist[BINS];
    __shared__ int lstart[BINS];
    __shared__ int cur[BINS];

    const int mode = *mode_p;
    int t = threadIdx.x;
    int blk = blockIdx.x;

    for (int j = t; j < BINS; j += 512) hist[j] = bcnt[j * BLK1 + blk];
    __syncthreads();

    // exclusive scan of hist[0..BINS) by wave 0: 13 bins/lane (64*13=832 >= 782)
    if (t < 64) {
        int base = t * 13;
        int run = 0;
        int loc[13];
#pragma unroll
        for (int u = 0; u < 13; ++u) {
            int idx = base + u;
            int v = (idx < BINS) ? hist[idx] : 0;
            loc[u] = run;
            run += v;
        }
        int inc = run;
        for (int o = 1; o < 64; o <<= 1) {
            int up = __shfl_up(inc, o);
            if (t >= o) inc += up;
        }
        int excl = inc - run;
#pragma unroll
        for (int u = 0; u < 13; ++u) {
            int idx = base + u;
            if (idx < BINS) { lstart[idx] = excl + loc[u]; cur[idx] = excl + loc[u]; }
        }
    }
    __syncthreads();

    // pass B: read edges, place into buf at sorted local position
    long long base = (long long)blk * CHUNK;
    int nthis = (int)(((long long)N_EDGES - base < (long long)CHUNK)
                      ? ((long long)N_EDGES - base) : (long long)CHUNK);
    for (int k = t; k < nthis; k += 512) {
        long long e = base + k;
        int d = load_idx(ei, (long long)N_EDGES + e, mode);
        if ((unsigned)d >= (unsigned)N_NODES) continue;
        int s = load_idx(ei, e, mode);
        s = min(max(s, 0), N_NODES - 1);         // memory-safety clamp (input always valid)
        int bin = d >> 8;
        int ld = d & 255;
        int pos = atomicAdd(&cur[bin], 1);       // local position in sorted order
        buf[pos] = s | (ld << 18);               // src:18 bits | local_dst:8 bits
    }
    __syncthreads();

    // write-out: wave w handles bins w, w+8, ... — contiguous coalesced bursts
    int wave = t >> 6, lane = t & 63;
    for (int bb = wave; bb < BINS; bb += 8) {
        int ls = lstart[bb];
        int ncnt = cur[bb] - ls;
        int gb = boff[bb * BLK1 + blk];
        for (int k = lane; k < ncnt; k += 64)
            ebuf[gb + k] = buf[ls + k];
    }
}

// ---------------------------------------------------------------- pass 5: per-bucket counting
// sort by COMPOSITE KEY (local_dst, src>>14) -> per-node contiguous edge lists in
// ascending coarse-src-window order (L2 temporal locality for p4b's gathers).
// nodeoff/deg derived from the bin scan; dis written into hpk row byte 20.
__global__ void p5_sort_kernel(int* __restrict__ ebuf,
                               const int* __restrict__ boff,
                               const int* __restrict__ total,
                               uint4* __restrict__ hpk,
                               int* __restrict__ nodeoff,
                               int* __restrict__ flag) {
    __shared__ int buf[SORT_CAP];       // 48 KB
    __shared__ int bins[SBINS];         // 16 KB: counts -> absolute excl scan -> cursors
    __shared__ int part[512];

    int b = blockIdx.x;
    int t = threadIdx.x;
    for (int j = t; j < SBINS; j += 512) bins[j] = 0;
    __syncthreads();

    int start = boff[b * BLK1];
    int end = (b < BINS - 1) ? boff[(b + 1) * BLK1] : *total;
    int n = end - start;
    bool fit = (n <= SORT_CAP);

    for (int k = t; k < n; k += 512) {
        int v = ebuf[start + k];
        int key = ((((unsigned)v) >> 18) << 4) | ((v & 0x3FFFF) >> 14);
        atomicAdd(&bins[key], 1);
        if (fit) buf[k] = v;
    }
    __syncthreads();

    // blocked exclusive scan of bins[0..SBINS) -> ABSOLUTE positions (+start)
    int base = t * 8;
    int loc[8];
    int run = 0;
#pragma unroll
    for (int u = 0; u < 8; ++u) { loc[u] = run; run += bins[base + u]; }
    part[t] = run;
    __syncthreads();
    for (int o = 1; o < 512; o <<= 1) {
        int u = (t >= o) ? part[t - o] : 0;
        __syncthreads();
        part[t] += u;
        __syncthreads();
    }
    int excl = part[t] - run;
#pragma unroll
    for (int u = 0; u < 8; ++u) bins[base + u] = start + excl + loc[u];
    __syncthreads();

    // nodeoff + dis (read bins BEFORE cursors get bumped)
    if (t < NPB) {
        int ns = bins[t * 16];
        nodeoff[b * NPB + t] = ns;
        int ne = (t < NPB - 1) ? bins[(t + 1) * 16] : end;
        int i = b * NPB + t;
        if (i < N_NODES) {
            float dis = rsqrtf((float)((ne - ns) + 1));   // +1 self-loop
            unsigned* rw = (unsigned*)(hpk + 2 * i + 1);
            rw[1] = __float_as_uint(dis);                 // byte 20 of the 32B row
        }
    }
    if (b == BINS - 1 && t == 0) nodeoff[BINS * NPB] = end;
    if (t == 0) flag[b] = fit ? 1 : 0;
    __syncthreads();

    if (!fit) return;
    // scatter back in (ld, src-window) order; bins[] cursors are ABSOLUTE
    for (int k = t; k < n; k += 512) {
        int v = buf[k];
        int key = ((((unsigned)v) >> 18) << 4) | ((v & 0x3FFFF) >> 14);
        int pos = atomicAdd(&bins[key], 1);
        ebuf[pos] = v;
    }
}

// ---------------------------------------------------------------- init2: h = (x @ W) * dis,
// packed fp16 into 32B rows {10 fp16, fp32 dis, pad} — one cache line serves 2 rows.
__global__ void init2_kernel(const float* __restrict__ x,
                             const float* __restrict__ Wg,
                             uint4* __restrict__ hpk) {
    __shared__ float Ws[F_IN * F_HID];
    for (int t = threadIdx.x; t < F_IN * F_HID; t += blockDim.x) Ws[t] = Wg[t];
    __syncthreads();

    int i = blockIdx.x * blockDim.x + threadIdx.x;
    if (i >= N_NODES) return;

    float acc[F_HID];
#pragma unroll
    for (int f = 0; f < F_HID; ++f) acc[f] = 0.0f;

    const float* xr = x + (long long)i * F_IN;
#pragma unroll
    for (int k = 0; k < F_IN; ++k) {
        float xv = xr[k];
#pragma unroll
        for (int f = 0; f < F_HID; ++f) acc[f] += xv * Ws[k * F_HID + f];
    }

    const unsigned* rro = (const unsigned*)(hpk + 2 * i + 1);
    unsigned disbits = rro[1];                 // dis written by p5
    float di = __uint_as_float(disbits);

    unsigned pk[5];
#pragma unroll
    for (int k = 0; k < 5; ++k) {
        __half lo = __float2half(acc[2 * k] * di);
        __half hi = __float2half(acc[2 * k + 1] * di);
        pk[k] = ((unsigned)__half_as_ushort(hi) << 16) | (unsigned)__half_as_ushort(lo);
    }
    hpk[2 * i]     = make_uint4(pk[0], pk[1], pk[2], pk[3]);
    hpk[2 * i + 1] = make_uint4(pk[4], disbits, 0u, 0u);
}

// ---------------------------------------------------------------- pass 4b: per-node register
// gather-accumulate (NO atomics). Grid = 2 blocks/bucket, 128 nodes/block,
// 4 threads/node (parity-4 split, batch-4 => 16 loads in flight per node),
// shfl_xor(1)+shfl_xor(2) combine. nt loads for ebuf, nt stores for out.
__global__ void __launch_bounds__(512, 8)
p4b_acc_kernel(const int* __restrict__ ebuf,
               const int* __restrict__ nodeoff,
               const int* __restrict__ flag,
               const uint4* __restrict__ hpk,
               const float* __restrict__ b_gcn,
               const float* __restrict__ W_fc,
               const float* __restrict__ b_fc,
               float* __restrict__ out) {
    __shared__ float accs[128 * ACCP];   // fallback arm only
    __shared__ float Wfs[F_HID * F_OUT];
    __shared__ float bfs[F_OUT];
    __shared__ float bgs[F_HID];

    int bb = blockIdx.x >> 1;            // bucket
    int half = blockIdx.x & 1;           // which 128-node half
    int t = threadIdx.x;                 // 0..511
    int jl = t >> 2;                     // local node 0..127
    int par = t & 3;                     // parity within node quad
    if (t < F_HID * F_OUT) Wfs[t] = W_fc[t];
    if (t < F_OUT) bfs[t] = b_fc[t];
    if (t < F_HID) bgs[t] = b_gcn[t];
    __syncthreads();

    float* hidden = out;                               // [N, F_HID]
    floatx4* o24 = reinterpret_cast<floatx4*>(out + (long long)N_NODES * F_HID);

    int i = bb * NPB + half * 128 + jl;
    bool valid = (i < N_NODES);
    float acc[F_HID];
#pragma unroll
    for (int f = 0; f < F_HID; ++f) acc[f] = 0.0f;

    if (flag[bb]) {
        // ---------- fast arm: (ld, src-window)-sorted, register accumulation ----------
        int rs = valid ? nodeoff[i] : 0;
        int re = valid ? nodeoff[i + 1] : 0;
        for (int k0 = rs + par; k0 < re; k0 += 16) {   // this thread: k0, k0+4, k0+8, k0+12
            unsigned v[4]; uint4 qa[4]; unsigned qb[4];
#pragma unroll
            for (int u = 0; u < 4; ++u)
                v[u] = (unsigned)__builtin_nontemporal_load(ebuf + min(k0 + 4 * u, re - 1));
#pragma unroll
            for (int u = 0; u < 4; ++u) {
                int s = v[u] & 0x3FFFF;
                qa[u] = hpk[2 * s];                    // same 64B line
                qb[u] = ((const unsigned*)(hpk + 2 * s + 1))[0];
            }
#pragma unroll
            for (int u = 0; u < 4; ++u) {
                if (k0 + 4 * u < re) {
                    float2 f01 = up2(qa[u].x), f23 = up2(qa[u].y);
                    float2 f45 = up2(qa[u].z), f67 = up2(qa[u].w);
                    float2 f89 = up2(qb[u]);
                    acc[0] += f01.x; acc[1] += f01.y;
                    acc[2] += f23.x; acc[3] += f23.y;
                    acc[4] += f45.x; acc[5] += f45.y;
                    acc[6] += f67.x; acc[7] += f67.y;
                    acc[8] += f89.x; acc[9] += f89.y;
                }
            }
        }
    } else {
        // ---------- fallback arm: unsorted bucket, LDS atomics (never taken for valid input) ----
        for (int j = t; j < 128 * ACCP; j += blockDim.x) accs[j] = 0.0f;
        __syncthreads();
        int start = nodeoff[bb * NPB];
        int end = (bb < BINS - 1) ? nodeoff[(bb + 1) * NPB] : nodeoff[BINS * NPB];
        for (int e = start + t; e < end; e += blockDim.x) {
            unsigned v = (unsigned)ebuf[e];
            int s = v & 0x3FFFF;
            int ld = v >> 18;
            if ((ld >> 7) != half) continue;           // only this block's half
            uint4 qa = hpk[2 * s];
            unsigned qb = ((const unsigned*)(hpk + 2 * s + 1))[0];
            float2 f01 = up2(qa.x), f23 = up2(qa.y), f45 = up2(qa.z), f67 = up2(qa.w), f89 = up2(qb);
            float* a = &accs[(ld - half * 128) * ACCP];
            atomicAdd(a + 0, f01.x); atomicAdd(a + 1, f01.y);
            atomicAdd(a + 2, f23.x); atomicAdd(a + 3, f23.y);
            atomicAdd(a + 4, f45.x); atomicAdd(a + 5, f45.y);
            atomicAdd(a + 6, f67.x); atomicAdd(a + 7, f67.y);
            atomicAdd(a + 8, f89.x); atomicAdd(a + 9, f89.y);
        }
        __syncthreads();
        if (par == 0) {                  // one lane per node takes the LDS sum; others stay 0
#pragma unroll
            for (int f = 0; f < F_HID; ++f) acc[f] = accs[jl * ACCP + f];
        }
    }

    // quad-combine: acc[node] = sum of 4 lanes
#pragma unroll
    for (int f = 0; f < F_HID; ++f) {
        acc[f] += __shfl_xor(acc[f], 1);
        acc[f] += __shfl_xor(acc[f], 2);
    }

    if (!valid || par) return;

    uint4 qa = hpk[2 * i];
    uint2 qb = *((const uint2*)(hpk + 2 * i + 1));
    float di = __uint_as_float(qb.y);
    float2 f01 = up2(qa.x), f23 = up2(qa.y), f45 = up2(qa.z), f67 = up2(qa.w), f89 = up2(qb.x);
    float hp[F_HID] = {f01.x, f01.y, f23.x, f23.y, f45.x, f45.y, f67.x, f67.y, f89.x, f89.y};

    float hv[F_HID];
#pragma unroll
    for (int f = 0; f < F_HID; ++f) {
        hv[f] = (acc[f] + hp[f]) * di + bgs[f];    // (sum_nbrs h' + h'[i]) * dis[i] + b
        __builtin_nontemporal_store(hv[f], hidden + (long long)i * F_HID + f);
    }
    floatx4 o;
#pragma unroll
    for (int jj = 0; jj < F_OUT; ++jj) {
        float vv = bfs[jj];
#pragma unroll
        for (int f = 0; f < F_HID; ++f) vv += hv[f] * Wfs[f * F_OUT + jj];
        o[jj] = fmaxf(vv, 0.0f);
    }
    __builtin_nontemporal_store(o, o24 + i);
}

// ================================================================ FALLBACK (atomic scatter, small ws)
__global__ void fb_init_kernel(const float* __restrict__ x, const float* __restrict__ Wg,
                               float* __restrict__ hpad, float* __restrict__ deg,
                               float* __restrict__ hidden) {
    __shared__ float Ws[F_IN * F_HID];
    for (int t = threadIdx.x; t < F_IN * F_HID; t += blockDim.x) Ws[t] = Wg[t];
    __syncthreads();
    int i = blockIdx.x * blockDim.x + threadIdx.x;
    if (i >= N_NODES) return;
    float acc[F_HID];
#pragma unroll
    for (int f = 0; f < F_HID; ++f) acc[f] = 0.0f;
    const float* xr = x + (long long)i * F_IN;
#pragma unroll
    for (int k = 0; k < F_IN; ++k) {
        float xv = xr[k];
#pragma unroll
        for (int f = 0; f < F_HID; ++f) acc[f] += xv * Ws[k * F_HID + f];
    }
    float* hr = hpad + (long long)i * HPAD;
#pragma unroll
    for (int f = 0; f < F_HID; ++f) hr[f] = acc[f];
    hr[10] = 0.0f; hr[11] = 0.0f;
    deg[i] = 1.0f;
    float* hd = hidden + (long long)i * F_HID;
#pragma unroll
    for (int f = 0; f < F_HID; ++f) hd[f] = 0.0f;
}

__global__ void fb_deg_kernel(const int* __restrict__ ei, const int* __restrict__ mode_p,
                              float* __restrict__ deg) {
    const int mode = *mode_p;
    long long e = (long long)blockIdx.x * blockDim.x + threadIdx.x;
    if (e >= N_EDGES) return;
    int d = load_idx(ei, (long long)N_EDGES + e, mode);
    if ((unsigned)d < (unsigned)N_NODES) atomicAdd(&deg[d], 1.0f);
}

__global__ void fb_scatter_kernel(const int* __restrict__ ei, const int* __restrict__ mode_p,
                                  const float* __restrict__ hpad, const float* __restrict__ deg,
                                  float* __restrict__ hidden) {
    const int mode = *mode_p;
    long long e = (long long)blockIdx.x * blockDim.x + threadIdx.x;
    if (e >= N_EDGES) return;
    int s = load_idx(ei, e, mode);
    int d = load_idx(ei, (long long)N_EDGES + e, mode);
    if ((unsigned)s >= (unsigned)N_NODES || (unsigned)d >= (unsigned)N_NODES) return;
    float norm = rsqrtf(deg[s]) * rsqrtf(deg[d]);
    const float4* h4 = reinterpret_cast<const float4*>(hpad + (long long)s * HPAD);
    float4 a = h4[0]; float4 b = h4[1]; float4 c = h4[2];
    float* o = hidden + (long long)d * F_HID;
    atomicAdd(o + 0, a.x * norm); atomicAdd(o + 1, a.y * norm);
    atomicAdd(o + 2, a.z * norm); atomicAdd(o + 3, a.w * norm);
    atomicAdd(o + 4, b.x * norm); atomicAdd(o + 5, b.y * norm);
    atomicAdd(o + 6, b.z * norm); atomicAdd(o + 7, b.w * norm);
    atomicAdd(o + 8, c.x * norm); atomicAdd(o + 9, c.y * norm);
}

__global__ void fb_finalize_kernel(const float* __restrict__ hpad, const float* __restrict__ deg,
                                   const float* __restrict__ b_gcn, const float* __restrict__ W_fc,
                                   const float* __restrict__ b_fc, float* __restrict__ out) {
    __shared__ float Wf[F_HID * F_OUT];
    __shared__ float bf_s[F_OUT];
    __shared__ float bg_s[F_HID];
    for (int t = threadIdx.x; t < F_HID * F_OUT; t += blockDim.x) Wf[t] = W_fc[t];
    if (threadIdx.x < F_OUT) bf_s[threadIdx.x] = b_fc[threadIdx.x];
    if (threadIdx.x < F_HID) bg_s[threadIdx.x] = b_gcn[threadIdx.x];
    __syncthreads();
    int i = blockIdx.x * blockDim.x + threadIdx.x;
    if (i >= N_NODES) return;
    float* hidden = out;
    float* o2 = out + (long long)N_NODES * F_HID;
    float inv = 1.0f / deg[i];
    const float* hr = hpad + (long long)i * HPAD;
    float* hd = hidden + (long long)i * F_HID;
    float hv[F_HID];
#pragma unroll
    for (int f = 0; f < F_HID; ++f) {
        hv[f] = hd[f] + hr[f] * inv + bg_s[f];
        hd[f] = hv[f];
    }
#pragma unroll
    for (int j = 0; j < F_OUT; ++j) {
        float o = bf_s[j];
#pragma unroll
        for (int f = 0; f < F_HID; ++f) o += hv[f] * Wf[f * F_OUT + j];
        o2[(long long)i * F_OUT + j] = fmaxf(o, 0.0f);
    }
}

// ---------------------------------------------------------------- launch
extern "C" void kernel_launch(void* const* d_in, const int* in_sizes, int n_in,
                              void* d_out, int out_size, void* d_ws, size_t ws_size,
                              hipStream_t stream) {
    const float* x  = (const float*)d_in[0];
    const int*   ei = (const int*)d_in[1];
    const float* Wg = (const float*)d_in[2];
    const float* bg = (const float*)d_in[3];
    const float* Wf = (const float*)d_in[4];
    const float* bf = (const float*)d_in[5];
    float* out = (float*)d_out;

    const int nblk_node = (N_NODES + 255) / 256;     // 782

    // main ws layout (~35.3 MB)
    uint4* hpk     = (uint4*)d_ws;                              // 2*(BINS*NPB) uint4 = 6.4MB
    int*   bcnt    = (int*)(hpk + 2 * (size_t)BINS * NPB);      // SCAN_L
    int*   boff    = bcnt + SCAN_L;                             // SCAN_L
    int*   bsum    = boff + SCAN_L;                             // 1024 (NA=598 used)
    int*   total   = bsum + 1024;                               // 1
    int*   nodeoff = total + 1;                                 // BINS*NPB+1
    int*   flag    = nodeoff + BINS * NPB + 1;                  // BINS
    int*   ebuf    = flag + BINS;                               // N_EDGES
    int*   mode    = ebuf + N_EDGES;                            // 1
    size_t need = (size_t)((char*)(mode + 1) - (char*)d_ws);

    if (ws_size >= need) {
        detect_mode_kernel<<<1, 64, 0, stream>>>(ei, mode);
        p1_count_kernel<<<BLK1, 512, 0, stream>>>(ei, mode, bcnt);
        scanA_kernel<<<NA, 512, 0, stream>>>(bcnt, bsum);
        scanB_kernel<<<1, 1024, 0, stream>>>(bsum, total);
        scanC_kernel<<<NA, 512, 0, stream>>>(bcnt, bsum, boff);
        p3_fill_kernel<<<BLK1, 512, 0, stream>>>(ei, mode, bcnt, boff, ebuf);
        p5_sort_kernel<<<BINS, 512, 0, stream>>>(ebuf, boff, total, hpk, nodeoff, flag);
        init2_kernel<<<nblk_node, 256, 0, stream>>>(x, Wg, hpk);
        p4b_acc_kernel<<<BINS * 2, 512, 0, stream>>>(ebuf, nodeoff, flag, hpk,
                                                     bg, Wf, bf, out);
    } else {
        // fallback: atomic scatter (~10.4 MB)
        float* hpad  = (float*)d_ws;
        float* degf  = hpad + (size_t)N_NODES * HPAD;
        int*   mode2 = (int*)(degf + N_NODES);
        const int nblk_edge = (N_EDGES + 255) / 256;
        detect_mode_kernel<<<1, 64, 0, stream>>>(ei, mode2);
        fb_init_kernel<<<nblk_node, 256, 0, stream>>>(x, Wg, hpad, degf, out);
        fb_deg_kernel<<<nblk_edge, 256, 0, stream>>>(ei, mode2, degf);
        fb_scatter_kernel<<<nblk_edge, 256, 0, stream>>>(ei, mode2, hpad, degf, out);
        fb_finalize_kernel<<<nblk_node, 256, 0, stream>>>(hpad, degf, bg, Wf, bf, out);
    }
}